// Round 5
// baseline (1634.573 us; speedup 1.0000x reference)
//
#include <hip/hip_runtime.h>
#include <hip/hip_bf16.h>
#include <cstdint>
#include <cstddef>

#define S_ 256
#define N_ 1024
#define H_ 512
#define AD_ 128

typedef __attribute__((ext_vector_type(8))) short short8;
typedef __attribute__((ext_vector_type(4))) float f32x4;

// pack 8 f32 -> 8 bf16 (RNE)
__device__ __forceinline__ short8 pack8(float4 a, float4 b) {
  union { short8 s; __hip_bfloat162 h[4]; } u;
  u.h[0] = __float22bfloat162_rn(make_float2(a.x, a.y));
  u.h[1] = __float22bfloat162_rn(make_float2(a.z, a.w));
  u.h[2] = __float22bfloat162_rn(make_float2(b.x, b.y));
  u.h[3] = __float22bfloat162_rn(make_float2(b.z, b.w));
  return u.s;
}

// ---------------------------------------------------------------------------
// K0: W1 [H][AD] f32 -> MFMA-fragment-ordered bf16 (B-frag = linear 16B/lane).
// ---------------------------------------------------------------------------
__global__ __launch_bounds__(256) void k_w1frag(
    const float* __restrict__ w1_pre, const float* __restrict__ w1_fol,
    unsigned short* __restrict__ w1f) {
  int idx = blockIdx.x * 256 + threadIdx.x;  // 0..65535
  int st = blockIdx.y;
  const float* w1 = st ? w1_fol : w1_pre;
  int j = idx & 7;
  int lane = (idx >> 3) & 63;
  int c = (idx >> 9) & 7;
  int kk = idx >> 12;
  int k = kk * 32 + ((lane >> 4) << 3) + j;
  int d = c * 16 + (lane & 15);
  __hip_bfloat16 hb = __float2bfloat16(w1[(size_t)k * AD_ + d]);
  w1f[(size_t)st * 65536 + idx] = *(unsigned short*)&hb;
}

// ---------------------------------------------------------------------------
// K1: inclusive prefix sum of is_valid -> pos (rank-1), per stream.
// ---------------------------------------------------------------------------
__global__ __launch_bounds__(1024) void k_scan(
    const int* __restrict__ valid_pre, const int* __restrict__ valid_fol,
    int* __restrict__ pos) {
  const int st = blockIdx.x;
  const int* valid = st ? valid_fol : valid_pre;
  __shared__ int buf[1024];
  const int t = threadIdx.x;
  buf[t] = valid[t];
  __syncthreads();
  for (int off = 1; off < 1024; off <<= 1) {
    int v = (t >= off) ? buf[t - off] : 0;
    __syncthreads();
    buf[t] += v;
    __syncthreads();
  }
  pos[st * N_ + t] = buf[t] - 1;
}

// ---------------------------------------------------------------------------
// K2: fused per-(n,stream). 1024 thr = 16 waves. Per pair:
//   4 subtiles of 64 rows x K=512: stage (FULL 2KB-row bursts -> bf16 ->
//   XOR-swizzled LDS, double-buffered) overlapped with MFMA compute
//   (waves 0-3). Then wave-0 softmax, then P3 from L3.
// ---------------------------------------------------------------------------
__global__ __launch_bounds__(1024) void k_fused(
    const float* __restrict__ emb_pre, const float* __restrict__ emb_fol,
    const unsigned short* __restrict__ w1f,
    const float* __restrict__ w2_pre, const float* __restrict__ w2_fol,
    const unsigned char* __restrict__ mask_pre, const unsigned char* __restrict__ mask_fol,
    const int* __restrict__ valid_pre, const int* __restrict__ valid_fol,
    const int* __restrict__ pos,
    float* __restrict__ out) {
  // LDS: As[2][64][64] short8 (128KB) | lg (2KB) | wl (1KB); part aliases As[0].
  __shared__ __align__(16) unsigned char smem[134144];
  short8 (*As0)[64] = (short8(*)[64])(smem);
  short8 (*As1)[64] = (short8(*)[64])(smem + 65536);
  float (*lg)[2]    = (float(*)[2])(smem + 131072);
  float* wl         = (float*)(smem + 133120);
  float (*part)[128][4] = (float(*)[128][4])(smem);  // alias As0 (dead in P3)

  const int t = threadIdx.x;
  const int w = t >> 6, lane = t & 63;
  const int r16 = lane & 15, kq = lane >> 4;

  const int st = blockIdx.x & 1;
  const int nbase = blockIdx.x >> 1;
  const float* __restrict__ emb = st ? emb_fol : emb_pre;
  const float* __restrict__ w2  = st ? w2_fol : w2_pre;
  const unsigned char* __restrict__ mask = st ? mask_fol : mask_pre;
  const int* __restrict__ valid = st ? valid_fol : valid_pre;
  const unsigned short* __restrict__ bb = w1f + (size_t)st * 65536 + (size_t)lane * 8;

  const int sg = t >> 7, hc = t & 127, hh = hc * 4;
  const size_t RSTRIDE = (size_t)N_ * H_;   // between s-rows

  for (int i = 0; i < 8; ++i) {
    const int n = nbase + i * 128;
    const int v = valid[n];
    int np = pos[st * N_ + n]; if (np < 0) np = 0;
    const float* __restrict__ embn = emb + (size_t)np * H_;  // row s at embn + s*RSTRIDE

    uchar4 mkb = {0, 0, 0, 0};
    if (w == 0) mkb = *(const uchar4*)(mask + (size_t)np * S_ + lane * 4);

    // ---- stage subtile 0 (rows 0..63) -> As0, all 16 waves, 4 rows each
    for (int r = w; r < 64; r += 16) {
      const float* src = embn + (size_t)r * RSTRIDE + lane * 8;
      float4 u0 = *(const float4*)src;
      float4 u1 = *(const float4*)(src + 4);
      As0[r][lane ^ (r & 7)] = pack8(u0, u1);
    }
    __syncthreads();

    // ---- subtile loop: waves 4-15 stage t+1, waves 0-3 compute t
    for (int tt = 0; tt < 4; ++tt) {
      if (w >= 4) {
        if (tt < 3) {
          short8 (*Aw)[64] = ((tt + 1) & 1) ? As1 : As0;
          const int s0 = (tt + 1) * 64;
          for (int r = w - 4; r < 64; r += 12) {
            const float* src = embn + (size_t)(s0 + r) * RSTRIDE + lane * 8;
            float4 u0 = *(const float4*)src;
            float4 u1 = *(const float4*)(src + 4);
            Aw[r][lane ^ (r & 7)] = pack8(u0, u1);
          }
        }
      } else {
        short8 (*Ar)[64] = (tt & 1) ? As1 : As0;
        const int lrow = w * 16 + r16;
        const int sw = r16 & 7;
        f32x4 acc[8];
#pragma unroll
        for (int c = 0; c < 8; ++c) acc[c] = (f32x4){0.f, 0.f, 0.f, 0.f};
#pragma unroll
        for (int kk = 0; kk < 16; ++kk) {
          short8 a = Ar[lrow][(kk * 4 + kq) ^ sw];
          const unsigned short* bp = bb + kk * 4096;
#pragma unroll
          for (int c = 0; c < 8; ++c) {
            short8 b = *(const short8*)(bp + c * 512);
            acc[c] = __builtin_amdgcn_mfma_f32_16x16x32_bf16(a, b, acc[c], 0, 0, 0);
          }
        }
        // epilogue: tanh, @W2, 16-lane reduce, write logits
        float w2v0[8], w2v1[8];
#pragma unroll
        for (int c = 0; c < 8; ++c) {
          w2v0[c] = w2[(c * 16 + r16) * 2 + 0];
          w2v1[c] = w2[(c * 16 + r16) * 2 + 1];
        }
#pragma unroll
        for (int q = 0; q < 4; ++q) {
          float p0 = 0.f, p1 = 0.f;
#pragma unroll
          for (int c = 0; c < 8; ++c) {
            float th = tanhf(acc[c][q]);
            p0 += th * w2v0[c];
            p1 += th * w2v1[c];
          }
          p0 += __shfl_xor(p0, 1); p0 += __shfl_xor(p0, 2);
          p0 += __shfl_xor(p0, 4); p0 += __shfl_xor(p0, 8);
          p1 += __shfl_xor(p1, 1); p1 += __shfl_xor(p1, 2);
          p1 += __shfl_xor(p1, 4); p1 += __shfl_xor(p1, 8);
          if (r16 == 0) {
            int row = tt * 64 + w * 16 + kq * 4 + q;
            lg[row][0] = p0;
            lg[row][1] = p1;
          }
        }
      }
      __syncthreads();
    }

    // ---- softmax (wave 0, pure shfl)
    if (w == 0) {
      float l0[4], l1[4];
      bool mk[4];
#pragma unroll
      for (int j = 0; j < 4; ++j) {
        l0[j] = lg[lane * 4 + j][0];
        l1[j] = lg[lane * 4 + j][1];
      }
      mk[0] = mkb.x != 0; mk[1] = mkb.y != 0; mk[2] = mkb.z != 0; mk[3] = mkb.w != 0;
      float q0[4], q1[4];
#pragma unroll
      for (int r = 0; r < 2; ++r) {
        float* lv = r ? l1 : l0;
        float* qq = r ? q1 : q0;
        float m1 = fmaxf(fmaxf(lv[0], lv[1]), fmaxf(lv[2], lv[3]));
#pragma unroll
        for (int off = 32; off; off >>= 1) m1 = fmaxf(m1, __shfl_xor(m1, off));
        float e[4], s1 = 0.f;
#pragma unroll
        for (int j = 0; j < 4; ++j) { e[j] = __expf(lv[j] - m1); s1 += e[j]; }
#pragma unroll
        for (int off = 32; off; off >>= 1) s1 += __shfl_xor(s1, off);
        float inv1 = 1.f / s1;
        float vv[4];
#pragma unroll
        for (int j = 0; j < 4; ++j) vv[j] = mk[j] ? -INFINITY : e[j] * inv1;
        float m2 = fmaxf(fmaxf(vv[0], vv[1]), fmaxf(vv[2], vv[3]));
#pragma unroll
        for (int off = 32; off; off >>= 1) m2 = fmaxf(m2, __shfl_xor(m2, off));
        float e2[4], s2 = 0.f;
#pragma unroll
        for (int j = 0; j < 4; ++j) { e2[j] = mk[j] ? 0.f : __expf(vv[j] - m2); s2 += e2[j]; }
#pragma unroll
        for (int off = 32; off; off >>= 1) s2 += __shfl_xor(s2, off);
        float inv2 = 1.f / s2;
#pragma unroll
        for (int j = 0; j < 4; ++j) qq[j] = e2[j] * inv2;
      }
      float4 wv;
      wv.x = 0.5f * (q0[0] + q1[0]);
      wv.y = 0.5f * (q0[1] + q1[1]);
      wv.z = 0.5f * (q0[2] + q1[2]);
      wv.w = 0.5f * (q0[3] + q1[3]);
      *(float4*)&wl[lane * 4] = wv;
    }
    __syncthreads();  // wl ready; As dead -> part may alias

    // ---- P3: PV from L3-resident f32 tile
    float ax = 0.f, ay = 0.f, az = 0.f, aw = 0.f;
#pragma unroll 8
    for (int s = sg; s < S_; s += 8) {
      float4 x = *(const float4*)(embn + (size_t)s * RSTRIDE + hh);
      float ww = wl[s];
      ax += ww * x.x; ay += ww * x.y; az += ww * x.z; aw += ww * x.w;
    }
    part[sg][hc][0] = ax; part[sg][hc][1] = ay;
    part[sg][hc][2] = az; part[sg][hc][3] = aw;
    __syncthreads();  // partials ready
    if (t < 128) {
      float4 r = {0.f, 0.f, 0.f, 0.f};
#pragma unroll
      for (int g = 0; g < 8; ++g) {
        r.x += part[g][t][0]; r.y += part[g][t][1];
        r.z += part[g][t][2]; r.w += part[g][t][3];
      }
      if (v <= 0) r = (float4){0.f, 0.f, 0.f, 0.f};
      *(float4*)&out[(size_t)n * 1024 + st * 512 + t * 4] = r;
    }
    __syncthreads();  // part (aliasing As0) consumed before next pair's stage
  }
}

// ---------------------------------------------------------------------------
extern "C" void kernel_launch(void* const* d_in, const int* in_sizes, int n_in,
                              void* d_out, int out_size, void* d_ws, size_t ws_size,
                              hipStream_t stream) {
  const float* emb_pre = (const float*)d_in[0];
  const float* emb_fol = (const float*)d_in[1];
  const unsigned char* mask_pre = (const unsigned char*)d_in[2];
  const unsigned char* mask_fol = (const unsigned char*)d_in[3];
  const int* valid_pre = (const int*)d_in[4];
  const int* valid_fol = (const int*)d_in[5];
  const float* w1_pre = (const float*)d_in[6];
  const float* w2_pre = (const float*)d_in[7];
  const float* w1_fol = (const float*)d_in[8];
  const float* w2_fol = (const float*)d_in[9];
  float* out = (float*)d_out;

  char* ws = (char*)d_ws;
  unsigned short* w1f = (unsigned short*)ws;          // 256 KiB
  int* pos = (int*)(ws + 262144);                     // 8 KiB

  hipLaunchKernelGGL(k_w1frag, dim3(256, 2), dim3(256), 0, stream,
                     w1_pre, w1_fol, w1f);
  hipLaunchKernelGGL(k_scan, dim3(2), dim3(1024), 0, stream,
                     valid_pre, valid_fol, pos);
  hipLaunchKernelGGL(k_fused, dim3(256), dim3(1024), 0, stream,
                     emb_pre, emb_fol, w1f, w2_pre, w2_fol,
                     mask_pre, mask_fol, valid_pre, valid_fol, pos, out);
}

// Round 6
// 520.886 us; speedup vs baseline: 3.1381x; 3.1381x over previous
//
#include <hip/hip_runtime.h>
#include <hip/hip_bf16.h>
#include <cstdint>
#include <cstddef>

#define S_ 256
#define N_ 1024
#define H_ 512
#define AD_ 128
static constexpr int M_TOTAL = N_ * S_;   // 262144 rows per stream (m = s*N + n)

typedef __attribute__((ext_vector_type(8))) short short8;
typedef __attribute__((ext_vector_type(4))) float f32x4;

// pack 8 f32 -> 8 bf16 (RNE)
__device__ __forceinline__ short8 pack8(float4 a, float4 b) {
  union { short8 s; __hip_bfloat162 h[4]; } u;
  u.h[0] = __float22bfloat162_rn(make_float2(a.x, a.y));
  u.h[1] = __float22bfloat162_rn(make_float2(a.z, a.w));
  u.h[2] = __float22bfloat162_rn(make_float2(b.x, b.y));
  u.h[3] = __float22bfloat162_rn(make_float2(b.z, b.w));
  return u.s;
}

// ---------------------------------------------------------------------------
// K0: W1 [H][AD] f32 -> MFMA-fragment-ordered bf16 (B-frag = linear 16B/lane).
// ---------------------------------------------------------------------------
__global__ __launch_bounds__(256) void k_w1frag(
    const float* __restrict__ w1_pre, const float* __restrict__ w1_fol,
    unsigned short* __restrict__ w1f) {
  int idx = blockIdx.x * 256 + threadIdx.x;  // 0..65535
  int st = blockIdx.y;
  const float* w1 = st ? w1_fol : w1_pre;
  int j = idx & 7;
  int lane = (idx >> 3) & 63;
  int c = (idx >> 9) & 7;
  int kk = idx >> 12;
  int k = kk * 32 + ((lane >> 4) << 3) + j;
  int d = c * 16 + (lane & 15);
  __hip_bfloat16 hb = __float2bfloat16(w1[(size_t)k * AD_ + d]);
  w1f[(size_t)st * 65536 + idx] = *(unsigned short*)&hb;
}

// ---------------------------------------------------------------------------
// K1: inclusive prefix sum of is_valid -> pos (rank-1), per stream.
// ---------------------------------------------------------------------------
__global__ __launch_bounds__(1024) void k_scan(
    const int* __restrict__ valid_pre, const int* __restrict__ valid_fol,
    int* __restrict__ pos) {
  const int st = blockIdx.x;
  const int* valid = st ? valid_fol : valid_pre;
  __shared__ int buf[1024];
  const int t = threadIdx.x;
  buf[t] = valid[t];
  __syncthreads();
  for (int off = 1; off < 1024; off <<= 1) {
    int v = (t >= off) ? buf[t - off] : 0;
    __syncthreads();
    buf[t] += v;
    __syncthreads();
  }
  pos[st * N_ + t] = buf[t] - 1;
}

// ---------------------------------------------------------------------------
// K2: logits GEMM in MEMORY ORDER: m = s*N + n, 64 consecutive m-rows per
// block = 128 KB contiguous HBM read. A: global->reg (no LDS, no K-loop
// barriers). B: L2-resident fragment buffer. logits[st][m][2].
// ---------------------------------------------------------------------------
__global__ __launch_bounds__(256) void k_logits(
    const float* __restrict__ emb_pre, const float* __restrict__ emb_fol,
    const unsigned short* __restrict__ w1f,
    const float* __restrict__ w2_pre, const float* __restrict__ w2_fol,
    float* __restrict__ logits) {
  const int bid = blockIdx.x;
  const int st = bid >> 12;                  // 4096 blocks per stream
  const int m0 = (bid & 4095) * 64;
  const float* __restrict__ emb = st ? emb_fol : emb_pre;
  const float* __restrict__ w2  = st ? w2_fol : w2_pre;

  const int t = threadIdx.x;
  const int w = t >> 6, lane = t & 63;
  const int r16 = lane & 15, kq = lane >> 4;
  const unsigned short* __restrict__ bb = w1f + (size_t)st * 65536 + (size_t)lane * 8;

  const float* a0 = emb + (size_t)(m0 + w * 16 + r16) * H_ + kq * 8;

  f32x4 acc[8];
#pragma unroll
  for (int c = 0; c < 8; ++c) acc[c] = (f32x4){0.f, 0.f, 0.f, 0.f};

  float4 x0 = *(const float4*)a0;
  float4 x1 = *(const float4*)(a0 + 4);
#pragma unroll
  for (int kk = 0; kk < 16; ++kk) {
    float4 y0, y1;
    if (kk < 15) {
      const float* ap = a0 + (kk + 1) * 32;
      y0 = *(const float4*)ap;
      y1 = *(const float4*)(ap + 4);
    }
    short8 a = pack8(x0, x1);
    const unsigned short* bp = bb + kk * 4096;
#pragma unroll
    for (int c = 0; c < 8; ++c) {
      short8 b = *(const short8*)(bp + c * 512);
      acc[c] = __builtin_amdgcn_mfma_f32_16x16x32_bf16(a, b, acc[c], 0, 0, 0);
    }
    if (kk < 15) { x0 = y0; x1 = y1; }
  }

  // epilogue: tanh (exp-form), @W2, 16-lane reduce, write logits
  float w2v0[8], w2v1[8];
#pragma unroll
  for (int c = 0; c < 8; ++c) {
    w2v0[c] = w2[(c * 16 + r16) * 2 + 0];
    w2v1[c] = w2[(c * 16 + r16) * 2 + 1];
  }
#pragma unroll
  for (int q = 0; q < 4; ++q) {
    float p0 = 0.f, p1 = 0.f;
#pragma unroll
    for (int c = 0; c < 8; ++c) {
      float xc = fminf(fmaxf(acc[c][q], -10.f), 10.f);
      float e  = __expf(2.f * xc);
      float th = (e - 1.f) / (e + 1.f);
      p0 += th * w2v0[c];
      p1 += th * w2v1[c];
    }
    p0 += __shfl_xor(p0, 1); p0 += __shfl_xor(p0, 2);
    p0 += __shfl_xor(p0, 4); p0 += __shfl_xor(p0, 8);
    p1 += __shfl_xor(p1, 1); p1 += __shfl_xor(p1, 2);
    p1 += __shfl_xor(p1, 4); p1 += __shfl_xor(p1, 8);
    if (r16 == 0) {
      int m = m0 + w * 16 + kq * 4 + q;
      logits[((size_t)st * M_TOTAL + m) * 2 + 0] = p0;
      logits[((size_t)st * M_TOTAL + m) * 2 + 1] = p1;
    }
  }
}

// ---------------------------------------------------------------------------
// K3: per (stream, n): double softmax over s (source space), fold r-mean.
// logits layout [st][s][n][2]; wbar [st][n][s].
// ---------------------------------------------------------------------------
template <bool MAXRED>
__device__ __forceinline__ float blockRed(float v, float* buf) {
#pragma unroll
  for (int off = 32; off; off >>= 1) {
    float o = __shfl_xor(v, off);
    v = MAXRED ? fmaxf(v, o) : (v + o);
  }
  __syncthreads();
  if ((threadIdx.x & 63) == 0) buf[threadIdx.x >> 6] = v;
  __syncthreads();
  float r = buf[0];
#pragma unroll
  for (int i = 1; i < 4; ++i) r = MAXRED ? fmaxf(r, buf[i]) : (r + buf[i]);
  return r;
}

__global__ __launch_bounds__(256) void k_softmax(
    const float* __restrict__ logits,
    const unsigned char* __restrict__ mask_pre, const unsigned char* __restrict__ mask_fol,
    float* __restrict__ wbar) {
  const int n  = blockIdx.x;
  const int st = blockIdx.y;
  const unsigned char* mask = st ? mask_fol : mask_pre;
  const int s = threadIdx.x;

  float2 l = *(const float2*)&logits[((size_t)st * M_TOTAL + (size_t)s * N_ + n) * 2];
  const bool mk = mask[(size_t)n * S_ + s] != 0;

  __shared__ float buf[4];
  float q[2];
  float lv[2] = {l.x, l.y};
#pragma unroll
  for (int r = 0; r < 2; ++r) {
    float m1 = blockRed<true>(lv[r], buf);
    float e1 = __expf(lv[r] - m1);
    float s1 = blockRed<false>(e1, buf);
    float p1 = e1 / s1;                       // first softmax (unmasked)
    float v  = mk ? -INFINITY : p1;           // mask the probabilities
    float m2 = blockRed<true>(v, buf);
    float e2 = mk ? 0.f : __expf(v - m2);
    float s2 = blockRed<false>(e2, buf);
    q[r] = e2 / s2;                           // second softmax
  }
  wbar[((size_t)st * N_ + n) * S_ + s] = 0.5f * (q[0] + q[1]);
}

// ---------------------------------------------------------------------------
// K4: PV in memory order. Block = (st, n-chunk of 16, s-half). Per s-step one
// 32 KB contiguous burst (16 adjacent n-rows x full H). part[st][sh][n][h].
// ---------------------------------------------------------------------------
__global__ __launch_bounds__(512) void k_pv2(
    const float* __restrict__ emb_pre, const float* __restrict__ emb_fol,
    const float* __restrict__ wbar,
    float* __restrict__ part) {
  const int bid = blockIdx.x;          // 0..255
  const int st  = bid >> 7;
  const int idx = bid & 127;
  const int nc  = idx >> 1;            // 0..63
  const int sh  = idx & 1;             // 0..1
  const int n0 = nc * 16, s0 = sh * 128;
  const float* __restrict__ emb = st ? emb_fol : emb_pre;

  const int t = threadIdx.x;
  const int nl = t >> 5;               // 0..15 (n-row within chunk)
  const int c0 = (t & 31) * 4;         // h-base; acc j covers c0 + j*128

  __shared__ float wl[16][128];
  for (int i = t; i < 2048; i += 512) {
    int j = i >> 7, sl = i & 127;
    wl[j][sl] = wbar[((size_t)st * N_ + n0 + j) * S_ + s0 + sl];
  }
  __syncthreads();

  float4 acc[4], cur[4], nxt[4];
#pragma unroll
  for (int j = 0; j < 4; ++j) acc[j] = (float4){0.f, 0.f, 0.f, 0.f};

  // s descending (most recently L3-resident rows first)
  const float* rowp = emb + ((size_t)(s0 + 127) * N_ + n0 + nl) * H_ + c0;
  const size_t SSTR = (size_t)N_ * H_;
#pragma unroll
  for (int j = 0; j < 4; ++j) cur[j] = *(const float4*)(rowp + j * 128);

  for (int sl = 127; sl >= 0; --sl) {
    const float* nrow = rowp - SSTR;
    if (sl > 0) {
#pragma unroll
      for (int j = 0; j < 4; ++j) nxt[j] = *(const float4*)(nrow + j * 128);
    }
    const float wv = wl[nl][sl];
#pragma unroll
    for (int j = 0; j < 4; ++j) {
      acc[j].x += wv * cur[j].x;
      acc[j].y += wv * cur[j].y;
      acc[j].z += wv * cur[j].z;
      acc[j].w += wv * cur[j].w;
    }
#pragma unroll
    for (int j = 0; j < 4; ++j) cur[j] = nxt[j];
    rowp = nrow;
  }

  float* pp = part + (((size_t)(st * 2 + sh) * N_) + n0 + nl) * H_ + c0;
#pragma unroll
  for (int j = 0; j < 4; ++j) *(float4*)(pp + j * 128) = acc[j];
}

// ---------------------------------------------------------------------------
// K5: combine s-halves + valid/pos gather -> out[n][st*512 + h].
// ---------------------------------------------------------------------------
__global__ __launch_bounds__(256) void k_combine(
    const float* __restrict__ part, const int* __restrict__ pos,
    const int* __restrict__ valid_pre, const int* __restrict__ valid_fol,
    float* __restrict__ out) {
  const int n = blockIdx.x, t = threadIdx.x;
  const int st = t >> 7;
  const int c = (t & 127) * 4;
  const int* valid = st ? valid_fol : valid_pre;
  float4 r = {0.f, 0.f, 0.f, 0.f};
  if (valid[n] > 0) {
    int np = pos[st * N_ + n]; if (np < 0) np = 0;
    float4 a = *(const float4*)&part[(((size_t)(st * 2 + 0) * N_) + np) * H_ + c];
    float4 b = *(const float4*)&part[(((size_t)(st * 2 + 1) * N_) + np) * H_ + c];
    r.x = a.x + b.x; r.y = a.y + b.y; r.z = a.z + b.z; r.w = a.w + b.w;
  }
  *(float4*)&out[(size_t)n * 1024 + st * 512 + c] = r;
}

// ---------------------------------------------------------------------------
extern "C" void kernel_launch(void* const* d_in, const int* in_sizes, int n_in,
                              void* d_out, int out_size, void* d_ws, size_t ws_size,
                              hipStream_t stream) {
  const float* emb_pre = (const float*)d_in[0];
  const float* emb_fol = (const float*)d_in[1];
  const unsigned char* mask_pre = (const unsigned char*)d_in[2];
  const unsigned char* mask_fol = (const unsigned char*)d_in[3];
  const int* valid_pre = (const int*)d_in[4];
  const int* valid_fol = (const int*)d_in[5];
  const float* w1_pre = (const float*)d_in[6];
  const float* w2_pre = (const float*)d_in[7];
  const float* w1_fol = (const float*)d_in[8];
  const float* w2_fol = (const float*)d_in[9];
  float* out = (float*)d_out;

  char* ws = (char*)d_ws;
  unsigned short* w1f = (unsigned short*)ws;                    // 256 KiB
  int*   pos    = (int*)(ws + 262144);                          // 8 KiB
  float* logits = (float*)(ws + 270336);                        // 4 MiB  [2][S][N][2]
  float* wbar   = (float*)(ws + 270336 + 4194304);              // 2 MiB  [2][N][S]
  float* part   = (float*)(ws + 270336 + 4194304 + 2097152);    // 8 MiB  [2][2][N][H]

  hipLaunchKernelGGL(k_w1frag, dim3(256, 2), dim3(256), 0, stream,
                     w1_pre, w1_fol, w1f);
  hipLaunchKernelGGL(k_scan, dim3(2), dim3(1024), 0, stream,
                     valid_pre, valid_fol, pos);
  hipLaunchKernelGGL(k_logits, dim3(8192), dim3(256), 0, stream,
                     emb_pre, emb_fol, w1f, w2_pre, w2_fol, logits);
  hipLaunchKernelGGL(k_softmax, dim3(N_, 2), dim3(256), 0, stream,
                     logits, mask_pre, mask_fol, wbar);
  hipLaunchKernelGGL(k_pv2, dim3(256), dim3(512), 0, stream,
                     emb_pre, emb_fol, wbar, part);
  hipLaunchKernelGGL(k_combine, dim3(N_), dim3(256), 0, stream,
                     part, pos, valid_pre, valid_fol, out);
}

// Round 7
// 483.006 us; speedup vs baseline: 3.3842x; 1.0784x over previous
//
#include <hip/hip_runtime.h>
#include <hip/hip_bf16.h>
#include <cstdint>
#include <cstddef>

#define S_ 256
#define N_ 1024
#define H_ 512
#define AD_ 128
static constexpr int M_TOTAL = N_ * S_;   // 262144 rows per stream (m = s*N + n)

typedef __attribute__((ext_vector_type(8))) short short8;
typedef __attribute__((ext_vector_type(4))) float f32x4;

// pack 8 f32 -> 8 bf16 (RNE)
__device__ __forceinline__ short8 pack8(float4 a, float4 b) {
  union { short8 s; __hip_bfloat162 h[4]; } u;
  u.h[0] = __float22bfloat162_rn(make_float2(a.x, a.y));
  u.h[1] = __float22bfloat162_rn(make_float2(a.z, a.w));
  u.h[2] = __float22bfloat162_rn(make_float2(b.x, b.y));
  u.h[3] = __float22bfloat162_rn(make_float2(b.z, b.w));
  return u.s;
}

// ---------------------------------------------------------------------------
// K0: W1 [H][AD] f32 -> MFMA-fragment-ordered bf16 (B-frag = linear 16B/lane).
// ---------------------------------------------------------------------------
__global__ __launch_bounds__(256) void k_w1frag(
    const float* __restrict__ w1_pre, const float* __restrict__ w1_fol,
    unsigned short* __restrict__ w1f) {
  int idx = blockIdx.x * 256 + threadIdx.x;  // 0..65535
  int st = blockIdx.y;
  const float* w1 = st ? w1_fol : w1_pre;
  int j = idx & 7;
  int lane = (idx >> 3) & 63;
  int c = (idx >> 9) & 7;
  int kk = idx >> 12;
  int k = kk * 32 + ((lane >> 4) << 3) + j;
  int d = c * 16 + (lane & 15);
  __hip_bfloat16 hb = __float2bfloat16(w1[(size_t)k * AD_ + d]);
  w1f[(size_t)st * 65536 + idx] = *(unsigned short*)&hb;
}

// ---------------------------------------------------------------------------
// K1: inclusive prefix sum of is_valid -> pos (rank-1), per stream.
// ---------------------------------------------------------------------------
__global__ __launch_bounds__(1024) void k_scan(
    const int* __restrict__ valid_pre, const int* __restrict__ valid_fol,
    int* __restrict__ pos) {
  const int st = blockIdx.x;
  const int* valid = st ? valid_fol : valid_pre;
  __shared__ int buf[1024];
  const int t = threadIdx.x;
  buf[t] = valid[t];
  __syncthreads();
  for (int off = 1; off < 1024; off <<= 1) {
    int v = (t >= off) ? buf[t - off] : 0;
    __syncthreads();
    buf[t] += v;
    __syncthreads();
  }
  pos[st * N_ + t] = buf[t] - 1;
}

// ---------------------------------------------------------------------------
// K2: logits GEMM in memory order, 32 rows/wave (2 A-fragments share each
// B-fragment), 3-slot software-pipelined A loads (fully static after unroll).
// Block 256 thr = 4 waves = 128 rows. Grid 4096. logits[st][m][2].
// ---------------------------------------------------------------------------
__global__ __launch_bounds__(256) void k_logits(
    const float* __restrict__ emb_pre, const float* __restrict__ emb_fol,
    const unsigned short* __restrict__ w1f,
    const float* __restrict__ w2_pre, const float* __restrict__ w2_fol,
    float* __restrict__ logits) {
  const int bid = blockIdx.x;
  const int st = bid >> 11;                  // 2048 blocks per stream
  const int m0 = (bid & 2047) * 128;
  const float* __restrict__ emb = st ? emb_fol : emb_pre;
  const float* __restrict__ w2  = st ? w2_fol : w2_pre;

  const int t = threadIdx.x;
  const int w = t >> 6, lane = t & 63;
  const int r16 = lane & 15, kq = lane >> 4;
  const unsigned short* __restrict__ bb = w1f + (size_t)st * 65536 + (size_t)lane * 8;

  // wave owns rows m0 + w*32 + f*16 + r16, f in {0,1}
  const float* a0 = emb + (size_t)(m0 + w * 32 + r16) * H_ + kq * 8;

  f32x4 acc[2][8];
#pragma unroll
  for (int f = 0; f < 2; ++f)
#pragma unroll
    for (int c = 0; c < 8; ++c) acc[f][c] = (f32x4){0.f, 0.f, 0.f, 0.f};

  float4 xb[3][2][2];  // [slot][frag][half] — all indices static after unroll
#pragma unroll
  for (int p = 0; p < 3; ++p)
#pragma unroll
    for (int f = 0; f < 2; ++f) {
      const float* ap = a0 + f * (16 * H_) + p * 32;
      xb[p][f][0] = *(const float4*)ap;
      xb[p][f][1] = *(const float4*)(ap + 4);
    }

#pragma unroll
  for (int kk = 0; kk < 16; ++kk) {
    const int sl = kk % 3;
    // B fragments for this kk (shared by both A fragments)
    short8 b[8];
    const unsigned short* bp = bb + kk * 4096;
#pragma unroll
    for (int c = 0; c < 8; ++c) b[c] = *(const short8*)(bp + c * 512);
    // consume slot sl
    short8 af0 = pack8(xb[sl][0][0], xb[sl][0][1]);
    short8 af1 = pack8(xb[sl][1][0], xb[sl][1][1]);
    // refill slot sl with kk+3 (keeps ~2-3 steps of HBM loads in flight)
    if (kk + 3 < 16) {
#pragma unroll
      for (int f = 0; f < 2; ++f) {
        const float* ap = a0 + f * (16 * H_) + (kk + 3) * 32;
        xb[sl][f][0] = *(const float4*)ap;
        xb[sl][f][1] = *(const float4*)(ap + 4);
      }
    }
#pragma unroll
    for (int c = 0; c < 8; ++c) {
      acc[0][c] = __builtin_amdgcn_mfma_f32_16x16x32_bf16(af0, b[c], acc[0][c], 0, 0, 0);
      acc[1][c] = __builtin_amdgcn_mfma_f32_16x16x32_bf16(af1, b[c], acc[1][c], 0, 0, 0);
    }
  }

  // epilogue: tanh (exp-form), @W2, 16-lane reduce, write logits
  float w2v0[8], w2v1[8];
#pragma unroll
  for (int c = 0; c < 8; ++c) {
    w2v0[c] = w2[(c * 16 + r16) * 2 + 0];
    w2v1[c] = w2[(c * 16 + r16) * 2 + 1];
  }
#pragma unroll
  for (int f = 0; f < 2; ++f) {
#pragma unroll
    for (int q = 0; q < 4; ++q) {
      float p0 = 0.f, p1 = 0.f;
#pragma unroll
      for (int c = 0; c < 8; ++c) {
        float xc = fminf(fmaxf(acc[f][c][q], -10.f), 10.f);
        float e  = __expf(2.f * xc);
        float th = (e - 1.f) / (e + 1.f);
        p0 += th * w2v0[c];
        p1 += th * w2v1[c];
      }
      p0 += __shfl_xor(p0, 1); p0 += __shfl_xor(p0, 2);
      p0 += __shfl_xor(p0, 4); p0 += __shfl_xor(p0, 8);
      p1 += __shfl_xor(p1, 1); p1 += __shfl_xor(p1, 2);
      p1 += __shfl_xor(p1, 4); p1 += __shfl_xor(p1, 8);
      if (r16 == 0) {
        int m = m0 + w * 32 + f * 16 + kq * 4 + q;
        logits[((size_t)st * M_TOTAL + m) * 2 + 0] = p0;
        logits[((size_t)st * M_TOTAL + m) * 2 + 1] = p1;
      }
    }
  }
}

// ---------------------------------------------------------------------------
// K3: per (stream, n): double softmax over s (source space), fold r-mean.
// logits layout [st][s][n][2]; wbar [st][n][s].
// ---------------------------------------------------------------------------
template <bool MAXRED>
__device__ __forceinline__ float blockRed(float v, float* buf) {
#pragma unroll
  for (int off = 32; off; off >>= 1) {
    float o = __shfl_xor(v, off);
    v = MAXRED ? fmaxf(v, o) : (v + o);
  }
  __syncthreads();
  if ((threadIdx.x & 63) == 0) buf[threadIdx.x >> 6] = v;
  __syncthreads();
  float r = buf[0];
#pragma unroll
  for (int i = 1; i < 4; ++i) r = MAXRED ? fmaxf(r, buf[i]) : (r + buf[i]);
  return r;
}

__global__ __launch_bounds__(256) void k_softmax(
    const float* __restrict__ logits,
    const unsigned char* __restrict__ mask_pre, const unsigned char* __restrict__ mask_fol,
    float* __restrict__ wbar) {
  const int n  = blockIdx.x;
  const int st = blockIdx.y;
  const unsigned char* mask = st ? mask_fol : mask_pre;
  const int s = threadIdx.x;

  float2 l = *(const float2*)&logits[((size_t)st * M_TOTAL + (size_t)s * N_ + n) * 2];
  const bool mk = mask[(size_t)n * S_ + s] != 0;

  __shared__ float buf[4];
  float q[2];
  float lv[2] = {l.x, l.y};
#pragma unroll
  for (int r = 0; r < 2; ++r) {
    float m1 = blockRed<true>(lv[r], buf);
    float e1 = __expf(lv[r] - m1);
    float s1 = blockRed<false>(e1, buf);
    float p1 = e1 / s1;                       // first softmax (unmasked)
    float v  = mk ? -INFINITY : p1;           // mask the probabilities
    float m2 = blockRed<true>(v, buf);
    float e2 = mk ? 0.f : __expf(v - m2);
    float s2 = blockRed<false>(e2, buf);
    q[r] = e2 / s2;                           // second softmax
  }
  wbar[((size_t)st * N_ + n) * S_ + s] = 0.5f * (q[0] + q[1]);
}

// ---------------------------------------------------------------------------
// K4: PV in memory order. Block = (st, n-chunk of 16, s-half). Per s-step one
// 32 KB contiguous burst (16 adjacent n-rows x full H). part[st][sh][n][h].
// ---------------------------------------------------------------------------
__global__ __launch_bounds__(512) void k_pv2(
    const float* __restrict__ emb_pre, const float* __restrict__ emb_fol,
    const float* __restrict__ wbar,
    float* __restrict__ part) {
  const int bid = blockIdx.x;          // 0..255
  const int st  = bid >> 7;
  const int idx = bid & 127;
  const int nc  = idx >> 1;            // 0..63
  const int sh  = idx & 1;             // 0..1
  const int n0 = nc * 16, s0 = sh * 128;
  const float* __restrict__ emb = st ? emb_fol : emb_pre;

  const int t = threadIdx.x;
  const int nl = t >> 5;               // 0..15 (n-row within chunk)
  const int c0 = (t & 31) * 4;         // h-base; acc j covers c0 + j*128

  __shared__ float wl[16][128];
  for (int i = t; i < 2048; i += 512) {
    int j = i >> 7, sl = i & 127;
    wl[j][sl] = wbar[((size_t)st * N_ + n0 + j) * S_ + s0 + sl];
  }
  __syncthreads();

  float4 acc[4], cur[4], nxt[4];
#pragma unroll
  for (int j = 0; j < 4; ++j) acc[j] = (float4){0.f, 0.f, 0.f, 0.f};

  // s descending (most recently L3-resident rows first)
  const float* rowp = emb + ((size_t)(s0 + 127) * N_ + n0 + nl) * H_ + c0;
  const size_t SSTR = (size_t)N_ * H_;
#pragma unroll
  for (int j = 0; j < 4; ++j) cur[j] = *(const float4*)(rowp + j * 128);

  for (int sl = 127; sl >= 0; --sl) {
    const float* nrow = rowp - SSTR;
    if (sl > 0) {
#pragma unroll
      for (int j = 0; j < 4; ++j) nxt[j] = *(const float4*)(nrow + j * 128);
    }
    const float wv = wl[nl][sl];
#pragma unroll
    for (int j = 0; j < 4; ++j) {
      acc[j].x += wv * cur[j].x;
      acc[j].y += wv * cur[j].y;
      acc[j].z += wv * cur[j].z;
      acc[j].w += wv * cur[j].w;
    }
#pragma unroll
    for (int j = 0; j < 4; ++j) cur[j] = nxt[j];
    rowp = nrow;
  }

  float* pp = part + (((size_t)(st * 2 + sh) * N_) + n0 + nl) * H_ + c0;
#pragma unroll
  for (int j = 0; j < 4; ++j) *(float4*)(pp + j * 128) = acc[j];
}

// ---------------------------------------------------------------------------
// K5: combine s-halves + valid/pos gather -> out[n][st*512 + h].
// ---------------------------------------------------------------------------
__global__ __launch_bounds__(256) void k_combine(
    const float* __restrict__ part, const int* __restrict__ pos,
    const int* __restrict__ valid_pre, const int* __restrict__ valid_fol,
    float* __restrict__ out) {
  const int n = blockIdx.x, t = threadIdx.x;
  const int st = t >> 7;
  const int c = (t & 127) * 4;
  const int* valid = st ? valid_fol : valid_pre;
  float4 r = {0.f, 0.f, 0.f, 0.f};
  if (valid[n] > 0) {
    int np = pos[st * N_ + n]; if (np < 0) np = 0;
    float4 a = *(const float4*)&part[(((size_t)(st * 2 + 0) * N_) + np) * H_ + c];
    float4 b = *(const float4*)&part[(((size_t)(st * 2 + 1) * N_) + np) * H_ + c];
    r.x = a.x + b.x; r.y = a.y + b.y; r.z = a.z + b.z; r.w = a.w + b.w;
  }
  *(float4*)&out[(size_t)n * 1024 + st * 512 + c] = r;
}

// ---------------------------------------------------------------------------
extern "C" void kernel_launch(void* const* d_in, const int* in_sizes, int n_in,
                              void* d_out, int out_size, void* d_ws, size_t ws_size,
                              hipStream_t stream) {
  const float* emb_pre = (const float*)d_in[0];
  const float* emb_fol = (const float*)d_in[1];
  const unsigned char* mask_pre = (const unsigned char*)d_in[2];
  const unsigned char* mask_fol = (const unsigned char*)d_in[3];
  const int* valid_pre = (const int*)d_in[4];
  const int* valid_fol = (const int*)d_in[5];
  const float* w1_pre = (const float*)d_in[6];
  const float* w2_pre = (const float*)d_in[7];
  const float* w1_fol = (const float*)d_in[8];
  const float* w2_fol = (const float*)d_in[9];
  float* out = (float*)d_out;

  char* ws = (char*)d_ws;
  unsigned short* w1f = (unsigned short*)ws;                    // 256 KiB
  int*   pos    = (int*)(ws + 262144);                          // 8 KiB
  float* logits = (float*)(ws + 270336);                        // 4 MiB  [2][S][N][2]
  float* wbar   = (float*)(ws + 270336 + 4194304);              // 2 MiB  [2][N][S]
  float* part   = (float*)(ws + 270336 + 4194304 + 2097152);    // 8 MiB  [2][2][N][H]

  hipLaunchKernelGGL(k_w1frag, dim3(256, 2), dim3(256), 0, stream,
                     w1_pre, w1_fol, w1f);
  hipLaunchKernelGGL(k_scan, dim3(2), dim3(1024), 0, stream,
                     valid_pre, valid_fol, pos);
  hipLaunchKernelGGL(k_logits, dim3(4096), dim3(256), 0, stream,
                     emb_pre, emb_fol, w1f, w2_pre, w2_fol, logits);
  hipLaunchKernelGGL(k_softmax, dim3(N_, 2), dim3(256), 0, stream,
                     logits, mask_pre, mask_fol, wbar);
  hipLaunchKernelGGL(k_pv2, dim3(256), dim3(512), 0, stream,
                     emb_pre, emb_fol, wbar, part);
  hipLaunchKernelGGL(k_combine, dim3(N_), dim3(256), 0, stream,
                     part, pos, valid_pre, valid_fol, out);
}

// Round 8
// 455.394 us; speedup vs baseline: 3.5894x; 1.0606x over previous
//
#include <hip/hip_runtime.h>
#include <hip/hip_bf16.h>
#include <cstdint>
#include <cstddef>

#define S_ 256
#define N_ 1024
#define H_ 512
#define AD_ 128
static constexpr int M_TOTAL = N_ * S_;   // 262144 rows per stream (m = s*N + n)

typedef __attribute__((ext_vector_type(8))) short short8;
typedef __attribute__((ext_vector_type(4))) float f32x4;

// pack 8 f32 -> 8 bf16 (RNE)
__device__ __forceinline__ short8 pack8(float4 a, float4 b) {
  union { short8 s; __hip_bfloat162 h[4]; } u;
  u.h[0] = __float22bfloat162_rn(make_float2(a.x, a.y));
  u.h[1] = __float22bfloat162_rn(make_float2(a.z, a.w));
  u.h[2] = __float22bfloat162_rn(make_float2(b.x, b.y));
  u.h[3] = __float22bfloat162_rn(make_float2(b.z, b.w));
  return u.s;
}

// ---------------------------------------------------------------------------
// K0: W1 [H][AD] f32 -> MFMA-fragment-ordered bf16 (B-frag = linear 16B/lane).
// ---------------------------------------------------------------------------
__global__ __launch_bounds__(256) void k_w1frag(
    const float* __restrict__ w1_pre, const float* __restrict__ w1_fol,
    unsigned short* __restrict__ w1f) {
  int idx = blockIdx.x * 256 + threadIdx.x;  // 0..65535
  int st = blockIdx.y;
  const float* w1 = st ? w1_fol : w1_pre;
  int j = idx & 7;
  int lane = (idx >> 3) & 63;
  int c = (idx >> 9) & 7;
  int kk = idx >> 12;
  int k = kk * 32 + ((lane >> 4) << 3) + j;
  int d = c * 16 + (lane & 15);
  __hip_bfloat16 hb = __float2bfloat16(w1[(size_t)k * AD_ + d]);
  w1f[(size_t)st * 65536 + idx] = *(unsigned short*)&hb;
}

// ---------------------------------------------------------------------------
// K1: inclusive prefix sum of is_valid -> pos (rank-1), per stream.
// ---------------------------------------------------------------------------
__global__ __launch_bounds__(1024) void k_scan(
    const int* __restrict__ valid_pre, const int* __restrict__ valid_fol,
    int* __restrict__ pos) {
  const int st = blockIdx.x;
  const int* valid = st ? valid_fol : valid_pre;
  __shared__ int buf[1024];
  const int t = threadIdx.x;
  buf[t] = valid[t];
  __syncthreads();
  for (int off = 1; off < 1024; off <<= 1) {
    int v = (t >= off) ? buf[t - off] : 0;
    __syncthreads();
    buf[t] += v;
    __syncthreads();
  }
  pos[st * N_ + t] = buf[t] - 1;
}

// ---------------------------------------------------------------------------
// K2: logits GEMM in memory order. B staged ONCE into LDS (128 KB) so the
// K-loop's vmcnt stream is PURE A-loads (HBM) -> the 3-slot A prefetch
// window actually stays in flight (B uses lgkmcnt via ds_read_b128).
// Block 512 thr = 8 waves x 32 rows = 256 rows. Grid 2048. No K-loop barriers.
// ---------------------------------------------------------------------------
__global__ __launch_bounds__(512) void k_logits(
    const float* __restrict__ emb_pre, const float* __restrict__ emb_fol,
    const unsigned short* __restrict__ w1f,
    const float* __restrict__ w2_pre, const float* __restrict__ w2_fol,
    float* __restrict__ logits) {
  __shared__ __align__(16) unsigned short Bs[65536];   // 128 KB: full W1 frags

  const int bid = blockIdx.x;
  const int st = bid >> 10;                  // 1024 blocks per stream
  const int m0 = (bid & 1023) * 256;
  const float* __restrict__ emb = st ? emb_fol : emb_pre;
  const float* __restrict__ w2  = st ? w2_fol : w2_pre;

  const int t = threadIdx.x;
  const int w = t >> 6, lane = t & 63;
  const int r16 = lane & 15, kq = lane >> 4;

  // stage B: linear 128 KB copy from L2-resident w1f
  {
    const uint4* src = (const uint4*)(w1f + (size_t)st * 65536);
    uint4* dst = (uint4*)Bs;
#pragma unroll
    for (int i = 0; i < 16; ++i) dst[t + i * 512] = src[t + i * 512];
  }
  __syncthreads();

  const unsigned short* bb = Bs + lane * 8;

  // wave owns rows m0 + w*32 + f*16 + r16, f in {0,1}
  const float* a0 = emb + (size_t)(m0 + w * 32 + r16) * H_ + kq * 8;

  f32x4 acc[2][8];
#pragma unroll
  for (int f = 0; f < 2; ++f)
#pragma unroll
    for (int c = 0; c < 8; ++c) acc[f][c] = (f32x4){0.f, 0.f, 0.f, 0.f};

  float4 xb[3][2][2];  // [slot][frag][half] — all static after full unroll
#pragma unroll
  for (int p = 0; p < 3; ++p)
#pragma unroll
    for (int f = 0; f < 2; ++f) {
      const float* ap = a0 + f * (16 * H_) + p * 32;
      xb[p][f][0] = *(const float4*)ap;
      xb[p][f][1] = *(const float4*)(ap + 4);
    }

#pragma unroll
  for (int kk = 0; kk < 16; ++kk) {
    const int sl = kk % 3;
    // B fragments for this kk from LDS (lgkmcnt — does not touch vmcnt)
    short8 b[8];
    const unsigned short* bp = bb + kk * 4096;
#pragma unroll
    for (int c = 0; c < 8; ++c) b[c] = *(const short8*)(bp + c * 512);
    // consume A slot sl (loads issued 3 iterations ago)
    short8 af0 = pack8(xb[sl][0][0], xb[sl][0][1]);
    short8 af1 = pack8(xb[sl][1][0], xb[sl][1][1]);
    // refill slot sl with kk+3 (pure-A vmcnt stream -> stays in flight)
    if (kk + 3 < 16) {
#pragma unroll
      for (int f = 0; f < 2; ++f) {
        const float* ap = a0 + f * (16 * H_) + (kk + 3) * 32;
        xb[sl][f][0] = *(const float4*)ap;
        xb[sl][f][1] = *(const float4*)(ap + 4);
      }
    }
#pragma unroll
    for (int c = 0; c < 8; ++c) {
      acc[0][c] = __builtin_amdgcn_mfma_f32_16x16x32_bf16(af0, b[c], acc[0][c], 0, 0, 0);
      acc[1][c] = __builtin_amdgcn_mfma_f32_16x16x32_bf16(af1, b[c], acc[1][c], 0, 0, 0);
    }
  }

  // epilogue: tanh (exp-form), @W2, 16-lane reduce, write logits
  float w2v0[8], w2v1[8];
#pragma unroll
  for (int c = 0; c < 8; ++c) {
    w2v0[c] = w2[(c * 16 + r16) * 2 + 0];
    w2v1[c] = w2[(c * 16 + r16) * 2 + 1];
  }
#pragma unroll
  for (int f = 0; f < 2; ++f) {
#pragma unroll
    for (int q = 0; q < 4; ++q) {
      float p0 = 0.f, p1 = 0.f;
#pragma unroll
      for (int c = 0; c < 8; ++c) {
        float xc = fminf(fmaxf(acc[f][c][q], -10.f), 10.f);
        float e  = __expf(2.f * xc);
        float th = (e - 1.f) / (e + 1.f);
        p0 += th * w2v0[c];
        p1 += th * w2v1[c];
      }
      p0 += __shfl_xor(p0, 1); p0 += __shfl_xor(p0, 2);
      p0 += __shfl_xor(p0, 4); p0 += __shfl_xor(p0, 8);
      p1 += __shfl_xor(p1, 1); p1 += __shfl_xor(p1, 2);
      p1 += __shfl_xor(p1, 4); p1 += __shfl_xor(p1, 8);
      if (r16 == 0) {
        int m = m0 + w * 32 + f * 16 + kq * 4 + q;
        logits[((size_t)st * M_TOTAL + m) * 2 + 0] = p0;
        logits[((size_t)st * M_TOTAL + m) * 2 + 1] = p1;
      }
    }
  }
}

// ---------------------------------------------------------------------------
// K3: per (stream, n): double softmax over s (source space), fold r-mean.
// logits layout [st][s][n][2]; wbar [st][n][s].
// ---------------------------------------------------------------------------
template <bool MAXRED>
__device__ __forceinline__ float blockRed(float v, float* buf) {
#pragma unroll
  for (int off = 32; off; off >>= 1) {
    float o = __shfl_xor(v, off);
    v = MAXRED ? fmaxf(v, o) : (v + o);
  }
  __syncthreads();
  if ((threadIdx.x & 63) == 0) buf[threadIdx.x >> 6] = v;
  __syncthreads();
  float r = buf[0];
#pragma unroll
  for (int i = 1; i < 4; ++i) r = MAXRED ? fmaxf(r, buf[i]) : (r + buf[i]);
  return r;
}

__global__ __launch_bounds__(256) void k_softmax(
    const float* __restrict__ logits,
    const unsigned char* __restrict__ mask_pre, const unsigned char* __restrict__ mask_fol,
    float* __restrict__ wbar) {
  const int n  = blockIdx.x;
  const int st = blockIdx.y;
  const unsigned char* mask = st ? mask_fol : mask_pre;
  const int s = threadIdx.x;

  float2 l = *(const float2*)&logits[((size_t)st * M_TOTAL + (size_t)s * N_ + n) * 2];
  const bool mk = mask[(size_t)n * S_ + s] != 0;

  __shared__ float buf[4];
  float q[2];
  float lv[2] = {l.x, l.y};
#pragma unroll
  for (int r = 0; r < 2; ++r) {
    float m1 = blockRed<true>(lv[r], buf);
    float e1 = __expf(lv[r] - m1);
    float s1 = blockRed<false>(e1, buf);
    float p1 = e1 / s1;                       // first softmax (unmasked)
    float v  = mk ? -INFINITY : p1;           // mask the probabilities
    float m2 = blockRed<true>(v, buf);
    float e2 = mk ? 0.f : __expf(v - m2);
    float s2 = blockRed<false>(e2, buf);
    q[r] = e2 / s2;                           // second softmax
  }
  wbar[((size_t)st * N_ + n) * S_ + s] = 0.5f * (q[0] + q[1]);
}

// ---------------------------------------------------------------------------
// K4: PV in memory order. Block = (st, n-chunk of 16, s-half). Per s-step one
// 32 KB contiguous burst (16 adjacent n-rows x full H). part[st][sh][n][h].
// ---------------------------------------------------------------------------
__global__ __launch_bounds__(512) void k_pv2(
    const float* __restrict__ emb_pre, const float* __restrict__ emb_fol,
    const float* __restrict__ wbar,
    float* __restrict__ part) {
  const int bid = blockIdx.x;          // 0..255
  const int st  = bid >> 7;
  const int idx = bid & 127;
  const int nc  = idx >> 1;            // 0..63
  const int sh  = idx & 1;             // 0..1
  const int n0 = nc * 16, s0 = sh * 128;
  const float* __restrict__ emb = st ? emb_fol : emb_pre;

  const int t = threadIdx.x;
  const int nl = t >> 5;               // 0..15 (n-row within chunk)
  const int c0 = (t & 31) * 4;         // h-base; acc j covers c0 + j*128

  __shared__ float wl[16][128];
  for (int i = t; i < 2048; i += 512) {
    int j = i >> 7, sl = i & 127;
    wl[j][sl] = wbar[((size_t)st * N_ + n0 + j) * S_ + s0 + sl];
  }
  __syncthreads();

  float4 acc[4], cur[4], nxt[4];
#pragma unroll
  for (int j = 0; j < 4; ++j) acc[j] = (float4){0.f, 0.f, 0.f, 0.f};

  // s descending (most recently L3-resident rows first)
  const float* rowp = emb + ((size_t)(s0 + 127) * N_ + n0 + nl) * H_ + c0;
  const size_t SSTR = (size_t)N_ * H_;
#pragma unroll
  for (int j = 0; j < 4; ++j) cur[j] = *(const float4*)(rowp + j * 128);

  for (int sl = 127; sl >= 0; --sl) {
    const float* nrow = rowp - SSTR;
    if (sl > 0) {
#pragma unroll
      for (int j = 0; j < 4; ++j) nxt[j] = *(const float4*)(nrow + j * 128);
    }
    const float wv = wl[nl][sl];
#pragma unroll
    for (int j = 0; j < 4; ++j) {
      acc[j].x += wv * cur[j].x;
      acc[j].y += wv * cur[j].y;
      acc[j].z += wv * cur[j].z;
      acc[j].w += wv * cur[j].w;
    }
#pragma unroll
    for (int j = 0; j < 4; ++j) cur[j] = nxt[j];
    rowp = nrow;
  }

  float* pp = part + (((size_t)(st * 2 + sh) * N_) + n0 + nl) * H_ + c0;
#pragma unroll
  for (int j = 0; j < 4; ++j) *(float4*)(pp + j * 128) = acc[j];
}

// ---------------------------------------------------------------------------
// K5: combine s-halves + valid/pos gather -> out[n][st*512 + h].
// ---------------------------------------------------------------------------
__global__ __launch_bounds__(256) void k_combine(
    const float* __restrict__ part, const int* __restrict__ pos,
    const int* __restrict__ valid_pre, const int* __restrict__ valid_fol,
    float* __restrict__ out) {
  const int n = blockIdx.x, t = threadIdx.x;
  const int st = t >> 7;
  const int c = (t & 127) * 4;
  const int* valid = st ? valid_fol : valid_pre;
  float4 r = {0.f, 0.f, 0.f, 0.f};
  if (valid[n] > 0) {
    int np = pos[st * N_ + n]; if (np < 0) np = 0;
    float4 a = *(const float4*)&part[(((size_t)(st * 2 + 0) * N_) + np) * H_ + c];
    float4 b = *(const float4*)&part[(((size_t)(st * 2 + 1) * N_) + np) * H_ + c];
    r.x = a.x + b.x; r.y = a.y + b.y; r.z = a.z + b.z; r.w = a.w + b.w;
  }
  *(float4*)&out[(size_t)n * 1024 + st * 512 + c] = r;
}

// ---------------------------------------------------------------------------
extern "C" void kernel_launch(void* const* d_in, const int* in_sizes, int n_in,
                              void* d_out, int out_size, void* d_ws, size_t ws_size,
                              hipStream_t stream) {
  const float* emb_pre = (const float*)d_in[0];
  const float* emb_fol = (const float*)d_in[1];
  const unsigned char* mask_pre = (const unsigned char*)d_in[2];
  const unsigned char* mask_fol = (const unsigned char*)d_in[3];
  const int* valid_pre = (const int*)d_in[4];
  const int* valid_fol = (const int*)d_in[5];
  const float* w1_pre = (const float*)d_in[6];
  const float* w2_pre = (const float*)d_in[7];
  const float* w1_fol = (const float*)d_in[8];
  const float* w2_fol = (const float*)d_in[9];
  float* out = (float*)d_out;

  char* ws = (char*)d_ws;
  unsigned short* w1f = (unsigned short*)ws;                    // 256 KiB
  int*   pos    = (int*)(ws + 262144);                          // 8 KiB
  float* logits = (float*)(ws + 270336);                        // 4 MiB  [2][S][N][2]
  float* wbar   = (float*)(ws + 270336 + 4194304);              // 2 MiB  [2][N][S]
  float* part   = (float*)(ws + 270336 + 4194304 + 2097152);    // 8 MiB  [2][2][N][H]

  hipLaunchKernelGGL(k_w1frag, dim3(256, 2), dim3(256), 0, stream,
                     w1_pre, w1_fol, w1f);
  hipLaunchKernelGGL(k_scan, dim3(2), dim3(1024), 0, stream,
                     valid_pre, valid_fol, pos);
  hipLaunchKernelGGL(k_logits, dim3(2048), dim3(512), 0, stream,
                     emb_pre, emb_fol, w1f, w2_pre, w2_fol, logits);
  hipLaunchKernelGGL(k_softmax, dim3(N_, 2), dim3(256), 0, stream,
                     logits, mask_pre, mask_fol, wbar);
  hipLaunchKernelGGL(k_pv2, dim3(256), dim3(512), 0, stream,
                     emb_pre, emb_fol, wbar, part);
  hipLaunchKernelGGL(k_combine, dim3(N_), dim3(256), 0, stream,
                     part, pos, valid_pre, valid_fol, out);
}